// Round 6
// baseline (279.676 us; speedup 1.0000x reference)
//
#include <hip/hip_runtime.h>
#include <hip/hip_bf16.h>

// Problem constants
#define NB   64
#define NCDD 5
#define NHIS 100
#define ND   256
#define NK   10
#define TLD  23040          // T*L*D = 30*3*256
#define THRESH 0.1f
#define NEG_INF (-3.402823466e38f)
#define NROWS_HIS 6400      // 64*100
#define NROWS_CDD 320       // 64*5

typedef float f32x4 __attribute__((ext_vector_type(4)));

// ---------------------------------------------------------------------------
// Kernel 1: BYTE-IDENTICAL to R5 (attribution control).
// ---------------------------------------------------------------------------
__global__ __launch_bounds__(256) void proj_norm_all(
    const float* __restrict__ his_repr,
    const float* __restrict__ cdd_repr,
    const float* __restrict__ W,
    const float* __restrict__ bvec,
    float* __restrict__ Yall)
{
    __shared__ float red[4][8];
    const int r0  = blockIdx.x * 8;
    const int tid = threadIdx.x;

    const float* __restrict__ X = (r0 < NROWS_HIS)
        ? (his_repr + (size_t)r0 * ND)
        : (cdd_repr + (size_t)(r0 - NROWS_HIS) * ND);

    const float bias = bvec[tid];
    float acc[8];
#pragma unroll
    for (int r = 0; r < 8; ++r) acc[r] = bias;

    const float* wrow = W + (size_t)tid * ND;
    for (int k = 0; k < ND; k += 4) {
        const float4 w4 = *(const float4*)(wrow + k);
#pragma unroll
        for (int r = 0; r < 8; ++r) {
            const float4 x4 = *(const float4*)(X + (size_t)r * ND + k); // uniform
            acc[r] += w4.x * x4.x + w4.y * x4.y + w4.z * x4.z + w4.w * x4.w;
        }
    }

    const int wave = tid >> 6, lane = tid & 63;
#pragma unroll
    for (int r = 0; r < 8; ++r) {
        float v = acc[r] * acc[r];
        for (int off = 32; off; off >>= 1) v += __shfl_xor(v, off);
        if (lane == 0) red[wave][r] = v;
    }
    __syncthreads();

#pragma unroll
    for (int r = 0; r < 8; ++r) {
        const float s = red[0][r] + red[1][r] + red[2][r] + red[3][r];
        const float scale = 1.0f / fmaxf(sqrtf(s), 1e-12f);
        Yall[(size_t)(r0 + r) * ND + tid] = acc[r] * scale;
    }
}

// ---------------------------------------------------------------------------
// Kernel 2: BYTE-IDENTICAL to R5 (attribution control).
// ---------------------------------------------------------------------------
__global__ __launch_bounds__(512) void attn_topk_kernel(
    const float* __restrict__ cdd_p,
    const float* __restrict__ his_p,
    float* __restrict__ out_idx_f,
    int* __restrict__ ws_idx,
    float* __restrict__ ws_w)
{
    __shared__ f32x4 cdds[NCDD * 64];        // 5 rows * 1 KB
    __shared__ float attn_s[NCDD][128];      // padded
    const int b   = blockIdx.x;
    const int tid = threadIdx.x;

    for (int i = tid; i < NCDD * 64; i += 512)
        cdds[i] = ((const f32x4*)(cdd_p + (size_t)b * NCDD * ND))[i];
    __syncthreads();

    if (tid < NCDD * NHIS) {
        const int c = tid / NHIS, h = tid % NHIS;
        const f32x4* __restrict__ hrow =
            (const f32x4*)(his_p + ((size_t)b * NHIS + h) * ND);
        float a0 = 0.f, a1 = 0.f, a2 = 0.f, a3 = 0.f;
#pragma unroll 8
        for (int k = 0; k < 64; k += 4) {
            const f32x4 c0 = cdds[c * 64 + k],     h0 = hrow[k];
            const f32x4 c1 = cdds[c * 64 + k + 1], h1 = hrow[k + 1];
            const f32x4 c2 = cdds[c * 64 + k + 2], h2 = hrow[k + 2];
            const f32x4 c3 = cdds[c * 64 + k + 3], h3 = hrow[k + 3];
            a0 += c0[0]*h0[0] + c0[1]*h0[1] + c0[2]*h0[2] + c0[3]*h0[3];
            a1 += c1[0]*h1[0] + c1[1]*h1[1] + c1[2]*h1[2] + c1[3]*h1[3];
            a2 += c2[0]*h2[0] + c2[1]*h2[1] + c2[2]*h2[2] + c2[3]*h2[3];
            a3 += c3[0]*h3[0] + c3[1]*h3[1] + c3[2]*h3[2] + c3[3]*h3[3];
        }
        attn_s[c][h] = (a0 + a1) + (a2 + a3);
    }
    __syncthreads();

    const int wave = tid >> 6, lane = tid & 63;
    if (wave < NCDD) {
        const int c = wave;
        float v0 = attn_s[c][lane];
        float v1 = (lane + 64 < NHIS) ? attn_s[c][lane + 64] : NEG_INF;
#pragma unroll
        for (int k = 0; k < NK; ++k) {
            float lv; int li;
            if (v1 > v0) { lv = v1; li = lane + 64; }
            else         { lv = v0; li = lane; }            // tie -> lower idx
            for (int off = 1; off < 64; off <<= 1) {
                const float ov = __shfl_xor(lv, off);
                const int   oi = __shfl_xor(li, off);
                if (ov > lv || (ov == lv && oi < li)) { lv = ov; li = oi; }
            }
            if (lane == 0) {
                const float w = (lv < THRESH) ? 0.0f : lv;
                const int g = (b * NCDD + c) * NK + k;
                ws_idx[g] = li;
                ws_w[g]   = w;
                out_idx_f[g] = (float)li;
            }
            if (li == lane)            v0 = NEG_INF;
            else if (li == lane + 64)  v1 = NEG_INF;
        }
    }
}

// ---------------------------------------------------------------------------
// Kernel 3: BYTE-IDENTICAL to R4/R5. Launched TWICE this round (identical
// work, identical output — deterministic) to measure G = T6 - T5 directly.
// ---------------------------------------------------------------------------
__global__ __launch_bounds__(256) void gather_kernel(
    const float* __restrict__ his_emb,
    const int* __restrict__ ws_idx,
    const float* __restrict__ ws_w,
    float* __restrict__ out)
{
    const int orig = blockIdx.x;
    const int g = (orig & 7) * 400 + (orig >> 3);   // XCD-chunked (bijective)
    const int b = g / (NCDD * NK);
    const int tid = threadIdx.x;
    const float w = ws_w[g];

    f32x4* __restrict__ dst = (f32x4*)(out + (size_t)g * TLD);

    if (w == 0.0f) {
        const f32x4 z = {0.f, 0.f, 0.f, 0.f};
#pragma unroll
        for (int it = 0; it < 22; ++it) dst[tid + it * 256] = z;
        if (tid < 128) dst[22 * 256 + tid] = z;
        return;
    }

    const int idx = ws_idx[g];
    const f32x4* __restrict__ src =
        (const f32x4*)(his_emb + ((size_t)b * NHIS + idx) * TLD);

    f32x4 v[8];
#pragma unroll
    for (int j = 0; j < 8; ++j) v[j] = src[tid + j * 256];
#pragma unroll
    for (int j = 0; j < 8; ++j) dst[tid + j * 256] = v[j] * w;
#pragma unroll
    for (int j = 0; j < 8; ++j) v[j] = src[tid + (8 + j) * 256];
#pragma unroll
    for (int j = 0; j < 8; ++j) dst[tid + (8 + j) * 256] = v[j] * w;
#pragma unroll
    for (int j = 0; j < 6; ++j) v[j] = src[tid + (16 + j) * 256];
#pragma unroll
    for (int j = 0; j < 6; ++j) dst[tid + (16 + j) * 256] = v[j] * w;
    if (tid < 128) {
        const int i = 22 * 256 + tid;
        f32x4 t = src[i];
        dst[i] = t * w;
    }
}

// ---------------------------------------------------------------------------
extern "C" void kernel_launch(void* const* d_in, const int* in_sizes, int n_in,
                              void* d_out, int out_size, void* d_ws, size_t ws_size,
                              hipStream_t stream)
{
    const float* cdd_repr = (const float*)d_in[0];   // (64,5,256)
    const float* his_repr = (const float*)d_in[1];   // (64,100,256)
    const float* his_emb  = (const float*)d_in[2];   // (64,100,30,3,256)
    const float* W_sel    = (const float*)d_in[3];   // (256,256)
    const float* b_sel    = (const float*)d_in[4];   // (256,)
    float* out = (float*)d_out;

    // Workspace layout
    char* ws = (char*)d_ws;
    float* Yall  = (float*)ws;                       // 6720 rows * 256 * 4
    float* his_p = Yall;                             // rows [0, 6400)
    float* cdd_p = Yall + (size_t)NROWS_HIS * ND;    // rows [6400, 6720)
    int*   idx_i = (int*)  (ws + 6881280);           // 3200*4
    float* w_w   = (float*)(ws + 6894080);           // 3200*4

    // Output: his_activated [73,728,000] then idx [3200] (as float values)
    float* out_idx_f = out + (size_t)NB * NCDD * NK * TLD;

    proj_norm_all<<<(NROWS_HIS + NROWS_CDD) / 8, 256, 0, stream>>>(
        his_repr, cdd_repr, W_sel, b_sel, Yall);
    attn_topk_kernel<<<NB, 512, 0, stream>>>(cdd_p, his_p,
                                             out_idx_f, idx_i, w_w);
    // Measurement round: gather launched TWICE (identical work & output).
    // G = T6 - T5;  P = T5 - G.
    gather_kernel<<<NB * NCDD * NK, 256, 0, stream>>>(his_emb, idx_i, w_w, out);
    gather_kernel<<<NB * NCDD * NK, 256, 0, stream>>>(his_emb, idx_i, w_w, out);
}